// Round 2
// baseline (313.331 us; speedup 1.0000x reference)
//
#include <hip/hip_runtime.h>

// EfficientAttention: N=8, C=256, H=W=128 (L=16384), HEADS=8, hc=32
// out = x + att,  att[n,h,cv,l] = sum_ck (ctx[ck,cv]/S[ck]) * softmax_ck(q)[ck,l]
// ctx[ck,cv] = sum_l exp(k[ck,l]) * v[cv,l],  S[ck] = sum_l exp(k[ck,l])
// (k logits ~N(0,0.32^2) -> exp without max-subtraction is safe)

typedef __attribute__((ext_vector_type(8))) short short8;
typedef __attribute__((ext_vector_type(4))) float f32x4;

#define NB     8
#define CCH    256
#define LSP    16384
#define NHEADS 8
#define HC     32

#define BN   128   // pixels per tile
#define NT   4     // tiles per block -> 512 px/block
#define EP   136   // ekt/vt pitch (shorts)
#define QP2  40    // qt2 pitch (shorts, 80B: 16B-aligned rows)

__device__ __forceinline__ unsigned short f2bf(float f) {
  union { float f; unsigned u; } v; v.f = f;
  unsigned r = v.u + 0x7fffu + ((v.u >> 16) & 1u);   // RNE
  return (unsigned short)(r >> 16);
}
__device__ __forceinline__ float bf2f(unsigned short b) {
  union { unsigned u; float f; } v; v.u = ((unsigned)b) << 16;
  return v.f;
}
__device__ __forceinline__ void gload_lds16(const unsigned short* g, unsigned short* l) {
  __builtin_amdgcn_global_load_lds(
      (const __attribute__((address_space(1))) unsigned int*)g,
      (__attribute__((address_space(3))) unsigned int*)l, 16, 0, 0);
}

// ---------------- kernel 0: weights -> bf16 head-grouped [k;v;q], zero ctx/S ----------------
__global__ void k_prep(const float* __restrict__ Wk, const float* __restrict__ bk,
                       const float* __restrict__ Wq, const float* __restrict__ bq,
                       const float* __restrict__ Wv, const float* __restrict__ bv,
                       unsigned short* __restrict__ Wb, float* __restrict__ bb,
                       float* __restrict__ ctx, float* __restrict__ S) {
  int idx = blockIdx.x * 256 + threadIdx.x;
  if (idx < NHEADS * 96 * CCH) {
    int c = idx & (CCH - 1);
    int row = (idx >> 8) % 96;
    int h = idx / (96 * CCH);
    int ch = h * HC;
    float val;
    if (row < HC)          val = Wk[(ch + row) * CCH + c];
    else if (row < 2 * HC) val = Wv[(ch + row - HC) * CCH + c];
    else                   val = Wq[(ch + row - 2 * HC) * CCH + c];
    Wb[idx] = f2bf(val);
  }
  if (idx < NHEADS * 96) {
    int row = idx % 96, h = idx / 96, ch = h * HC;
    float val;
    if (row < HC)          val = bk[ch + row];
    else if (row < 2 * HC) val = bv[ch + row - HC];
    else                   val = bq[ch + row - 2 * HC];
    bb[idx] = val;
  }
  if (idx < NB * NHEADS * HC * HC) ctx[idx] = 0.f;
  if (idx < NB * NHEADS * HC)      S[idx]   = 0.f;
}

// ---------------- kernel 0b: x [n][c][l] f32 -> xT [n][l][c] bf16 ----------------
__global__ __launch_bounds__(256)
void k_transpose(const float* __restrict__ x, unsigned short* __restrict__ xT) {
  __shared__ float tile[64][65];
  int b = blockIdx.x;
  int ct = b & 3;             // CCH/64
  int lt = (b >> 2) & 255;    // LSP/64
  int n  = b >> 10;
  int c0 = ct * 64, l0 = lt * 64;
  int t = threadIdx.x;
  int li = t & 63, cr = t >> 6;
  const float* xp = x + (size_t)n * CCH * LSP;
#pragma unroll
  for (int i = 0; i < 16; ++i) {
    int ci = cr * 16 + i;
    tile[ci][li] = xp[(size_t)(c0 + ci) * LSP + l0 + li];
  }
  __syncthreads();
  int ci2 = t & 63, lr = t >> 6;
  unsigned short* xo = xT + ((size_t)n * LSP + l0) * CCH + c0;
#pragma unroll
  for (int i = 0; i < 16; ++i) {
    int l = lr * 16 + i;
    xo[(size_t)l * CCH + ci2] = f2bf(tile[ci2][l]);
  }
}

// ---------------- kernel 1: fused QKV GEMM + streaming ctx/S + q transpose-out ----------------
// grid: 8n x 32 lgroups (512 px); block 512 thr = 8 waves. t-outer (x staged once),
// h-inner (W restaged from L2). LDS linear+XOR-swizzle, staged by global_load_lds.
__global__ __launch_bounds__(512, 2)
void k_qkv(const unsigned short* __restrict__ xT,
           const unsigned short* __restrict__ Wb, const float* __restrict__ bb,
           unsigned short* __restrict__ qbuf, float* __restrict__ ctx,
           float* __restrict__ S) {
  __shared__ unsigned short xt[BN * CCH];    // 64 KiB, swizzled chunks
  __shared__ unsigned short wt[96 * CCH];    // 48 KiB, swizzled chunks
  __shared__ unsigned short ekt[HC * EP];    // exp(k) bf16 [ck][l]
  __shared__ unsigned short vt[HC * EP];     // v bf16 [cv][l]
  __shared__ unsigned short qt2[BN * QP2];   // q bf16 [l][ck]

  int n  = (int)blockIdx.x >> 5;
  int lg = (int)blockIdx.x & 31;
  int l0 = lg * (BN * NT);
  int tid = threadIdx.x;
  int wid = tid >> 6, lane = tid & 63;
  int r16 = lane & 15, kg = lane >> 4;
  int rb  = (wid >> 2) * 48;     // 0 / 48
  int cbw = (wid & 3) * 32;      // 0/32/64/96
  int sw  = r16 & 7;

  const unsigned short* xTn = xT + (((size_t)n) << 14) * CCH;

  // stage W head hh: 48 instr (6/wave), dest linear, source chunk-XOR-swizzled
  auto stage_wt = [&](int hh) {
#pragma unroll
    for (int i = 0; i < 6; ++i) {
      int f = (wid * 6 + i) * 64 + lane;
      int row = f >> 5, c = f & 31;
      gload_lds16(Wb + (((size_t)(hh * 96 + row)) << 8) + ((c ^ (row & 7)) << 3),
                  wt + (size_t)(wid * 6 + i) * 512);
    }
  };
  // stage x tile tt: 64 instr (8/wave)
  auto stage_xt = [&](int tt) {
    int lbs = l0 + tt * BN;
#pragma unroll
    for (int i = 0; i < 8; ++i) {
      int f = (wid * 8 + i) * 64 + lane;
      int row = f >> 5, c = f & 31;
      gload_lds16(xTn + (((size_t)(lbs + row)) << 8) + ((c ^ (row & 7)) << 3),
                  xt + (size_t)(wid * 8 + i) * 512);
    }
  };

  stage_xt(0);
  stage_wt(0);

  for (int t = 0; t < NT; ++t) {
    int lb = l0 + t * BN;
    for (int h = 0; h < NHEADS; ++h) {
      __syncthreads();   // stages drained (vmcnt0); prev post done

      float bias[3][4];
#pragma unroll
      for (int m = 0; m < 3; ++m)
#pragma unroll
        for (int r = 0; r < 4; ++r)
          bias[m][r] = bb[h * 96 + rb + m * 16 + kg * 4 + r];

      // ---- GEMM [96x256]x[256x128], wave tile 48x32 ----
      f32x4 acc[3][2];
#pragma unroll
      for (int m = 0; m < 3; ++m) { acc[m][0] = (f32x4){0,0,0,0}; acc[m][1] = (f32x4){0,0,0,0}; }
#pragma unroll
      for (int kk = 0; kk < 8; ++kk) {
        int ch0 = (((kk * 4 + kg) ^ sw) << 3);
        short8 b0 = *(const short8*)&xt[(cbw + r16) * 256 + ch0];
        short8 b1 = *(const short8*)&xt[(cbw + 16 + r16) * 256 + ch0];
#pragma unroll
        for (int m = 0; m < 3; ++m) {
          short8 a = *(const short8*)&wt[(rb + m * 16 + r16) * 256 + ch0];
          acc[m][0] = __builtin_amdgcn_mfma_f32_16x16x32_bf16(a, b0, acc[m][0], 0, 0, 0);
          acc[m][1] = __builtin_amdgcn_mfma_f32_16x16x32_bf16(a, b1, acc[m][1], 0, 0, 0);
        }
      }

      // ---- scatter: k->exp bf16 (+S partial), v->bf16, q->bf16 transposed ----
      float sk[2][4] = {{0.f,0.f,0.f,0.f},{0.f,0.f,0.f,0.f}};
#pragma unroll
      for (int m = 0; m < 3; ++m) {
        int base = rb + m * 16;        // 0,16,32,48,64,80 (uniform per wave,m)
        int cls = base >> 5;
        int rl = base + kg * 4;
#pragma unroll
        for (int r = 0; r < 4; ++r) {
#pragma unroll
          for (int nn = 0; nn < 2; ++nn) {
            float val = acc[m][nn][r] + bias[m][r];
            int col = cbw + nn * 16 + r16;
            int row = rl + r;
            if (cls == 0) {
              unsigned short us = f2bf(__expf(val));
              ekt[row * EP + col] = us;
              sk[m][r] += bf2f(us);                    // m in {0,1} here
            } else if (cls == 1) {
              vt[(row - 32) * EP + col] = f2bf(val);
            } else {
              qt2[col * QP2 + (row - 64)] = f2bf(val);
            }
          }
        }
      }
      // S partial flush (waves with rb==0 hold all k rows)
      if (rb == 0) {
#pragma unroll
        for (int m = 0; m < 2; ++m)
#pragma unroll
          for (int r = 0; r < 4; ++r) {
            float s = sk[m][r];
            s += __shfl_xor(s, 1); s += __shfl_xor(s, 2);
            s += __shfl_xor(s, 4); s += __shfl_xor(s, 8);
            if (r16 == 0) atomicAdd(&S[(n * NHEADS + h) * HC + m * 16 + kg * 4 + r], s);
          }
      }
      __syncthreads();   // scatter visible

      // issue next stages early so they fly under the post phase
      if (h < NHEADS - 1) stage_wt(h + 1);
      else if (t < NT - 1) { stage_xt(t + 1); stage_wt(0); }

      // ---- post: ctx MFMA (waves 0-3) / q-store (waves 4-7) ----
      if (wid < 4) {
        int tm = (wid >> 1) & 1, tn = wid & 1;
        f32x4 ac = {0.f, 0.f, 0.f, 0.f};
#pragma unroll
        for (int ks = 0; ks < 4; ++ks) {
          short8 af = *(const short8*)&ekt[(tm * 16 + r16) * EP + ks * 32 + kg * 8];
          short8 bf = *(const short8*)&vt[(tn * 16 + r16) * EP + ks * 32 + kg * 8];
          ac = __builtin_amdgcn_mfma_f32_16x16x32_bf16(af, bf, ac, 0, 0, 0);
        }
        float* cp = ctx + ((size_t)(n * NHEADS + h) * HC + tm * 16) * HC + tn * 16;
#pragma unroll
        for (int r = 0; r < 4; ++r)
          atomicAdd(&cp[(kg * 4 + r) * HC + r16], ac[r]);
      } else {
        int w4 = wid & 3;
        size_t gb = ((size_t)(n * NHEADS + h) * LSP + lb) << 5;
#pragma unroll
        for (int iq = 0; iq < 2; ++iq) {
          int cq = w4 * 32 + iq * 16 + (lane >> 2), c4 = lane & 3;
          short8 d = *(const short8*)&qt2[cq * QP2 + c4 * 8];
          *(short8*)&qbuf[gb + ((size_t)cq << 5) + c4 * 8] = d;
        }
      }
    }
  }
}

// ---------------- kernel 2: ctx/S, transpose, -> bf16 ----------------
__global__ void k_norm(const float* __restrict__ ctx, const float* __restrict__ S,
                       unsigned short* __restrict__ ctxT) {
  int idx = blockIdx.x * 256 + threadIdx.x;  // 65536 = [n][h][ck][cv]
  int cv = idx & 31, ck = (idx >> 5) & 31, nh = idx >> 10;
  float v = ctx[idx] / S[(nh << 5) + ck];
  ctxT[(nh << 10) + (cv << 5) + ck] = f2bf(v);
}

// ---------------- kernel 3: att = ctxT (32x32) x softmax_ck(q) + residual ----------------
__global__ __launch_bounds__(256)
void k_att(const float* __restrict__ x, const unsigned short* __restrict__ qbuf,
           const unsigned short* __restrict__ ctxT, float* __restrict__ out) {
  int b = blockIdx.x;
  int lc = b & 63;           // 64 chunks of 256 pixels
  int nh = b >> 6;
  int h = nh & 7, n = nh >> 3;
  int tid = threadIdx.x, wid = tid >> 6, lane = tid & 63;
  int r16 = lane & 15, kg = lane >> 4;
  int lw = lc * 256 + wid * 64;

  const unsigned short* cp = ctxT + ((size_t)nh << 10);
  short8 a0 = *(const short8*)&cp[(r16 << 5) + kg * 8];          // A[cv][ck], cv 0-15
  short8 a1 = *(const short8*)&cp[((16 + r16) << 5) + kg * 8];   // cv 16-31
  const unsigned short* qb = qbuf + (((size_t)nh * LSP) << 5);
  const float* xp = x   + ((size_t)n * CCH + (size_t)h * HC) * LSP;
  float*       op = out + ((size_t)n * CCH + (size_t)h * HC) * LSP;

#pragma unroll
  for (int t = 0; t < 4; ++t) {
    int l = lw + t * 16;
    short8 bq = *(const short8*)&qb[((size_t)(l + r16) << 5) + kg * 8];  // q logits [l][ck]
    // softmax over ck: 8 in-lane + 4-lane (kg) shfl reduce
    float qv[8];
#pragma unroll
    for (int j = 0; j < 8; ++j) qv[j] = bf2f((unsigned short)bq[j]);
    float mx = qv[0];
#pragma unroll
    for (int j = 1; j < 8; ++j) mx = fmaxf(mx, qv[j]);
    mx = fmaxf(mx, __shfl_xor(mx, 16));
    mx = fmaxf(mx, __shfl_xor(mx, 32));
    float ss = 0.f;
#pragma unroll
    for (int j = 0; j < 8; ++j) { qv[j] = __expf(qv[j] - mx); ss += qv[j]; }
    ss += __shfl_xor(ss, 16);
    ss += __shfl_xor(ss, 32);
    float inv = 1.f / ss;
    short8 bf;
#pragma unroll
    for (int j = 0; j < 8; ++j) bf[j] = (short)f2bf(qv[j] * inv);

    f32x4 d0 = {0, 0, 0, 0}, d1 = {0, 0, 0, 0};
    d0 = __builtin_amdgcn_mfma_f32_16x16x32_bf16(a0, bf, d0, 0, 0, 0);
    d1 = __builtin_amdgcn_mfma_f32_16x16x32_bf16(a1, bf, d1, 0, 0, 0);
#pragma unroll
    for (int r = 0; r < 4; ++r) {
      int cv = kg * 4 + r;
      int li = l + r16;
      op[(size_t)cv * LSP + li]        = d0[r] + xp[(size_t)cv * LSP + li];
      op[(size_t)(cv + 16) * LSP + li] = d1[r] + xp[(size_t)(cv + 16) * LSP + li];
    }
  }
}

extern "C" void kernel_launch(void* const* d_in, const int* in_sizes, int n_in,
                              void* d_out, int out_size, void* d_ws, size_t ws_size,
                              hipStream_t stream) {
  (void)in_sizes; (void)n_in; (void)out_size; (void)ws_size;
  const float* x  = (const float*)d_in[0];
  const float* Wk = (const float*)d_in[1];
  const float* bk = (const float*)d_in[2];
  const float* Wq = (const float*)d_in[3];
  const float* bq = (const float*)d_in[4];
  const float* Wv = (const float*)d_in[5];
  const float* bv = (const float*)d_in[6];
  float* out = (float*)d_out;

  char* ws = (char*)d_ws;
  unsigned short* Wb   = (unsigned short*)(ws + 0);          //   393216
  float*          bbp  = (float*)(ws + 393216);              //     3072
  float*          ctx  = (float*)(ws + 396288);              //   262144
  unsigned short* ctxT = (unsigned short*)(ws + 658432);     //   131072
  float*          S    = (float*)(ws + 789504);              //     8192
  unsigned short* qbuf = (unsigned short*)(ws + 797696);     // 67108864
  unsigned short* xT   = (unsigned short*)(ws + 67906560);   // 67108864 -> 135015424 total

  k_prep<<<768, 256, 0, stream>>>(Wk, bk, Wq, bq, Wv, bv, Wb, bbp, ctx, S);
  k_transpose<<<NB * 256 * 4, 256, 0, stream>>>(x, xT);
  k_qkv<<<256, 512, 0, stream>>>(xT, Wb, bbp, qbuf, ctx, S);
  k_norm<<<256, 256, 0, stream>>>(ctx, S, ctxT);
  k_att<<<NB * NHEADS * 64, 256, 0, stream>>>(x, qbuf, ctxT, out);
}

// Round 3
// 307.055 us; speedup vs baseline: 1.0204x; 1.0204x over previous
//
#include <hip/hip_runtime.h>

// EfficientAttention: N=8, C=256, H=W=128 (L=16384), HEADS=8, hc=32
// out = x + att,  att[n,h,cv,l] = sum_ck (ctx[ck,cv]/S[ck]) * softmax_ck(q)[ck,l]
// ctx[ck,cv] = sum_l exp(k[ck,l]) * v[cv,l],  S[ck] = sum_l exp(k[ck,l])
// (k logits ~N(0,0.32^2) -> exp without max-subtraction is safe)

typedef __attribute__((ext_vector_type(8))) short short8;
typedef __attribute__((ext_vector_type(4))) float f32x4;

#define NB     8
#define CCH    256
#define LSP    16384
#define NHEADS 8
#define HC     32

#define BN   128   // pixels per tile
#define NT   4     // tiles per block -> 512 px/block
#define EP   136   // ekt/vt pitch (shorts): row stride 272B -> slot (r16+kg)&7, balanced b128
#define QP2  40    // qt2 pitch (shorts)

__device__ __forceinline__ unsigned short f2bf(float f) {
  union { float f; unsigned u; } v; v.f = f;
  unsigned r = v.u + 0x7fffu + ((v.u >> 16) & 1u);   // RNE
  return (unsigned short)(r >> 16);
}
__device__ __forceinline__ float bf2f(unsigned short b) {
  union { unsigned u; float f; } v; v.u = ((unsigned)b) << 16;
  return v.f;
}
__device__ __forceinline__ void gload_lds16(const unsigned short* g, unsigned short* l) {
  __builtin_amdgcn_global_load_lds(
      (const __attribute__((address_space(1))) unsigned int*)g,
      (__attribute__((address_space(3))) unsigned int*)l, 16, 0, 0);
}

// ---------------- kernel 0: weights -> bf16 head-grouped [k;v;q], zero ctx/S ----------------
__global__ void k_prep(const float* __restrict__ Wk, const float* __restrict__ bk,
                       const float* __restrict__ Wq, const float* __restrict__ bq,
                       const float* __restrict__ Wv, const float* __restrict__ bv,
                       unsigned short* __restrict__ Wb, float* __restrict__ bb,
                       float* __restrict__ ctx, float* __restrict__ S) {
  int idx = blockIdx.x * 256 + threadIdx.x;
  if (idx < NHEADS * 96 * CCH) {
    int c = idx & (CCH - 1);
    int row = (idx >> 8) % 96;
    int h = idx / (96 * CCH);
    int ch = h * HC;
    float val;
    if (row < HC)          val = Wk[(ch + row) * CCH + c];
    else if (row < 2 * HC) val = Wv[(ch + row - HC) * CCH + c];
    else                   val = Wq[(ch + row - 2 * HC) * CCH + c];
    Wb[idx] = f2bf(val);
  }
  if (idx < NHEADS * 96) {
    int row = idx % 96, h = idx / 96, ch = h * HC;
    float val;
    if (row < HC)          val = bk[ch + row];
    else if (row < 2 * HC) val = bv[ch + row - HC];
    else                   val = bq[ch + row - 2 * HC];
    bb[idx] = val;
  }
  if (idx < NB * NHEADS * HC * HC) ctx[idx] = 0.f;
  if (idx < NB * NHEADS * HC)      S[idx]   = 0.f;
}

// ---------------- kernel 0b: x [n][c][l] f32 -> xT [n][l][c] bf16 ----------------
__global__ __launch_bounds__(256)
void k_transpose(const float* __restrict__ x, unsigned short* __restrict__ xT) {
  __shared__ float tile[64][65];
  int b = blockIdx.x;
  int ct = b & 3;             // CCH/64
  int lt = (b >> 2) & 255;    // LSP/64
  int n  = b >> 10;
  int c0 = ct * 64, l0 = lt * 64;
  int t = threadIdx.x;
  int li = t & 63, cr = t >> 6;
  const float* xp = x + (size_t)n * CCH * LSP;
#pragma unroll
  for (int i = 0; i < 16; ++i) {
    int ci = cr * 16 + i;
    tile[ci][li] = xp[(size_t)(c0 + ci) * LSP + l0 + li];
  }
  __syncthreads();
  int ci2 = t & 63, lr = t >> 6;
  unsigned short* xo = xT + ((size_t)n * LSP + l0) * CCH + c0;
#pragma unroll
  for (int i = 0; i < 16; ++i) {
    int l = lr * 16 + i;
    xo[(size_t)l * CCH + ci2] = f2bf(tile[ci2][l]);
  }
}

// ---------------- kernel 1: fused QKV GEMM + streaming ctx/S + q transpose-out ----------------
// One head per block. grid 2048 = 8h x 8n x 32lg; bid = ((n*4+lg>>3)*8+h)*8 + (lg&7)
// so all 8 h-blocks of an (n,lg) x-slice run concurrently on ONE XCD (L2 reuse).
// W in registers (24 short8/lane), ctx/S in registers, double-buffered x-tile with
// counted vmcnt(1) so next-tile DMA stays in flight across the whole iteration.
__global__ __launch_bounds__(512, 2)
void k_qkv(const unsigned short* __restrict__ xT,
           const unsigned short* __restrict__ Wb, const float* __restrict__ bb,
           unsigned short* __restrict__ qbuf, float* __restrict__ ctx,
           float* __restrict__ S) {
  __shared__ unsigned short xt[2][BN * CCH];   // 2 x 64 KiB, swizzled chunks
  __shared__ unsigned short ekt[HC * EP];      // exp(k) bf16 [ck][l]
  __shared__ unsigned short vt[HC * EP];       // v bf16 [cv][l]
  __shared__ unsigned short qt2[BN * QP2];     // q bf16 [l][ck]

  int bid = (int)blockIdx.x;
  int xcd = bid & 7, qq = bid >> 3;
  int h = qq & 7, rest = qq >> 3;
  int lg = ((rest & 3) << 3) | xcd;   // 0..31
  int n  = rest >> 2;
  int l0 = lg * (BN * NT);

  int tid = threadIdx.x;
  int wid = tid >> 6, lane = tid & 63;
  int r16 = lane & 15, kg = lane >> 4;
  int rb  = (wid >> 2) * 48;     // 0 / 48
  int cbw = (wid & 3) * 32;      // 0/32/64/96
  int sw  = r16 & 7;

  const unsigned short* xTn = xT + (((size_t)n) << 14) * CCH;

  // stage x tile tt into xt[buf]: 8 gload_lds16 per wave, dest linear,
  // source chunk-XOR-swizzled (both-sides involution, rule 21)
  auto stage_xt = [&](int buf, int tt) {
    int lbs = l0 + tt * BN;
#pragma unroll
    for (int i = 0; i < 8; ++i) {
      int f = (wid * 8 + i) * 64 + lane;
      int row = f >> 5, c = f & 31;
      gload_lds16(xTn + (((size_t)(lbs + row)) << 8) + ((c ^ (row & 7)) << 3),
                  &xt[buf][(size_t)(wid * 8 + i) * 512]);
    }
  };

  stage_xt(0, 0);   // start DMA first

  // W fragments in registers: rows rb+m*16+r16, chunk kk*32+kg*8 (linear, no swizzle)
  short8 af[3][8];
  {
    const unsigned short* wsrc = Wb + (((size_t)(h * 96 + rb)) << 8);
#pragma unroll
    for (int m = 0; m < 3; ++m)
#pragma unroll
      for (int kk = 0; kk < 8; ++kk)
        af[m][kk] = *(const short8*)&wsrc[(((size_t)(m * 16 + r16)) << 8) + kk * 32 + kg * 8];
  }
  float bias[3][4];
#pragma unroll
  for (int m = 0; m < 3; ++m)
#pragma unroll
    for (int r = 0; r < 4; ++r)
      bias[m][r] = bb[h * 96 + rb + m * 16 + kg * 4 + r];

  f32x4 acc_ctx = {0.f, 0.f, 0.f, 0.f};
  float sk[2][4] = {{0.f,0.f,0.f,0.f},{0.f,0.f,0.f,0.f}};
  int cur = 0;

  for (int t = 0; t < NT; ++t) {
    int lb = l0 + t * BN;
    // barrier1: wait current tile's DMA (8/wave) complete; leave next-tile DMA in flight
    if (t == 0) { asm volatile("s_waitcnt vmcnt(0)" ::: "memory"); }
    else        { asm volatile("s_waitcnt vmcnt(1)" ::: "memory"); }
    __builtin_amdgcn_sched_barrier(0);
    __builtin_amdgcn_s_barrier();
    __builtin_amdgcn_sched_barrier(0);

    // ---- GEMM [96x256]x[256x128], wave tile 48x32, A from registers ----
    f32x4 acc[3][2];
#pragma unroll
    for (int m = 0; m < 3; ++m) { acc[m][0] = (f32x4){0,0,0,0}; acc[m][1] = (f32x4){0,0,0,0}; }
    const unsigned short* xb = &xt[cur][0];
#pragma unroll
    for (int kk = 0; kk < 8; ++kk) {
      int ch0 = (((kk * 4 + kg) ^ sw) << 3);
      short8 b0 = *(const short8*)&xb[(cbw + r16) * 256 + ch0];
      short8 b1 = *(const short8*)&xb[(cbw + 16 + r16) * 256 + ch0];
#pragma unroll
      for (int m = 0; m < 3; ++m) {
        acc[m][0] = __builtin_amdgcn_mfma_f32_16x16x32_bf16(af[m][kk], b0, acc[m][0], 0, 0, 0);
        acc[m][1] = __builtin_amdgcn_mfma_f32_16x16x32_bf16(af[m][kk], b1, acc[m][1], 0, 0, 0);
      }
    }

    // ---- scatter: k->exp bf16 (+S reg-accum), v->bf16, q->bf16 transposed ----
#pragma unroll
    for (int m = 0; m < 3; ++m) {
      int base = rb + m * 16;        // uniform per (wave,m)
      int cls = base >> 5;
      int rl = base + kg * 4;
#pragma unroll
      for (int r = 0; r < 4; ++r) {
#pragma unroll
        for (int nn = 0; nn < 2; ++nn) {
          float val = acc[m][nn][r] + bias[m][r];
          int col = cbw + nn * 16 + r16;
          int row = rl + r;
          if (cls == 0) {
            unsigned short us = f2bf(__expf(val));
            ekt[row * EP + col] = us;
            sk[m][r] += bf2f(us);                    // only m in {0,1} reach here
          } else if (cls == 1) {
            vt[(row - 32) * EP + col] = f2bf(val);
          } else {
            qt2[col * QP2 + (row - 64)] = f2bf(val);
          }
        }
      }
    }
    __syncthreads();   // barrier2: scatter visible (vmcnt(0) here drains only old qcopy store)

    // issue next tile's DMA now: flies under post phase + next GEMM
    if (t + 1 < NT) stage_xt(cur ^ 1, t + 1);

    // ---- post: ctx MFMA (waves 0-3, into registers) + q-copy (all waves) ----
    if (wid < 4) {
      int tm = (wid >> 1) & 1, tn = wid & 1;
#pragma unroll
      for (int ks = 0; ks < 4; ++ks) {
        short8 ea = *(const short8*)&ekt[(tm * 16 + r16) * EP + ks * 32 + kg * 8];
        short8 vb = *(const short8*)&vt[(tn * 16 + r16) * EP + ks * 32 + kg * 8];
        acc_ctx = __builtin_amdgcn_mfma_f32_16x16x32_bf16(ea, vb, acc_ctx, 0, 0, 0);
      }
    }
    {
      int px = tid >> 2, c4 = tid & 3;   // 128 px x 4 chunks of 8 ck
      short8 d = *(const short8*)&qt2[px * QP2 + c4 * 8];
      size_t gb = ((size_t)(n * NHEADS + h) * LSP + lb) << 5;
      *(short8*)&qbuf[gb + ((size_t)px << 5) + c4 * 8] = d;
    }
    cur ^= 1;
  }

  // ---- single flush per block: ctx quadrants + S partials ----
  if (wid < 4) {
    int tm = (wid >> 1) & 1, tn = wid & 1;
    float* cp = ctx + ((size_t)(n * NHEADS + h) * HC + tm * 16) * HC + tn * 16;
#pragma unroll
    for (int r = 0; r < 4; ++r)
      atomicAdd(&cp[(kg * 4 + r) * HC + r16], acc_ctx[r]);
  }
  if (rb == 0) {
#pragma unroll
    for (int m = 0; m < 2; ++m)
#pragma unroll
      for (int r = 0; r < 4; ++r) {
        float s = sk[m][r];
        s += __shfl_xor(s, 1); s += __shfl_xor(s, 2);
        s += __shfl_xor(s, 4); s += __shfl_xor(s, 8);
        if (r16 == 0) atomicAdd(&S[(n * NHEADS + h) * HC + m * 16 + kg * 4 + r], s);
      }
  }
}

// ---------------- kernel 2: ctx/S, transpose, -> bf16 ----------------
__global__ void k_norm(const float* __restrict__ ctx, const float* __restrict__ S,
                       unsigned short* __restrict__ ctxT) {
  int idx = blockIdx.x * 256 + threadIdx.x;  // 65536 = [n][h][ck][cv]
  int cv = idx & 31, ck = (idx >> 5) & 31, nh = idx >> 10;
  float v = ctx[idx] / S[(nh << 5) + ck];
  ctxT[(nh << 10) + (cv << 5) + ck] = f2bf(v);
}

// ---------------- kernel 3: att = ctxT (32x32) x softmax_ck(q) + residual ----------------
__global__ __launch_bounds__(256)
void k_att(const float* __restrict__ x, const unsigned short* __restrict__ qbuf,
           const unsigned short* __restrict__ ctxT, float* __restrict__ out) {
  int b = blockIdx.x;
  int lc = b & 63;           // 64 chunks of 256 pixels
  int nh = b >> 6;
  int h = nh & 7, n = nh >> 3;
  int tid = threadIdx.x, wid = tid >> 6, lane = tid & 63;
  int r16 = lane & 15, kg = lane >> 4;
  int lw = lc * 256 + wid * 64;

  const unsigned short* cp = ctxT + ((size_t)nh << 10);
  short8 a0 = *(const short8*)&cp[(r16 << 5) + kg * 8];          // A[cv][ck], cv 0-15
  short8 a1 = *(const short8*)&cp[((16 + r16) << 5) + kg * 8];   // cv 16-31
  const unsigned short* qb = qbuf + (((size_t)nh * LSP) << 5);
  const float* xp = x   + ((size_t)n * CCH + (size_t)h * HC) * LSP;
  float*       op = out + ((size_t)n * CCH + (size_t)h * HC) * LSP;

#pragma unroll
  for (int t = 0; t < 4; ++t) {
    int l = lw + t * 16;
    short8 bq = *(const short8*)&qb[((size_t)(l + r16) << 5) + kg * 8];  // q logits [l][ck]
    float qv[8];
#pragma unroll
    for (int j = 0; j < 8; ++j) qv[j] = bf2f((unsigned short)bq[j]);
    float mx = qv[0];
#pragma unroll
    for (int j = 1; j < 8; ++j) mx = fmaxf(mx, qv[j]);
    mx = fmaxf(mx, __shfl_xor(mx, 16));
    mx = fmaxf(mx, __shfl_xor(mx, 32));
    float ss = 0.f;
#pragma unroll
    for (int j = 0; j < 8; ++j) { qv[j] = __expf(qv[j] - mx); ss += qv[j]; }
    ss += __shfl_xor(ss, 16);
    ss += __shfl_xor(ss, 32);
    float inv = 1.f / ss;
    short8 bf;
#pragma unroll
    for (int j = 0; j < 8; ++j) bf[j] = (short)f2bf(qv[j] * inv);

    f32x4 d0 = {0, 0, 0, 0}, d1 = {0, 0, 0, 0};
    d0 = __builtin_amdgcn_mfma_f32_16x16x32_bf16(a0, bf, d0, 0, 0, 0);
    d1 = __builtin_amdgcn_mfma_f32_16x16x32_bf16(a1, bf, d1, 0, 0, 0);
#pragma unroll
    for (int r = 0; r < 4; ++r) {
      int cv = kg * 4 + r;
      int li = l + r16;
      op[(size_t)cv * LSP + li]        = d0[r] + xp[(size_t)cv * LSP + li];
      op[(size_t)(cv + 16) * LSP + li] = d1[r] + xp[(size_t)(cv + 16) * LSP + li];
    }
  }
}

extern "C" void kernel_launch(void* const* d_in, const int* in_sizes, int n_in,
                              void* d_out, int out_size, void* d_ws, size_t ws_size,
                              hipStream_t stream) {
  (void)in_sizes; (void)n_in; (void)out_size; (void)ws_size;
  const float* x  = (const float*)d_in[0];
  const float* Wk = (const float*)d_in[1];
  const float* bk = (const float*)d_in[2];
  const float* Wq = (const float*)d_in[3];
  const float* bq = (const float*)d_in[4];
  const float* Wv = (const float*)d_in[5];
  const float* bv = (const float*)d_in[6];
  float* out = (float*)d_out;

  char* ws = (char*)d_ws;
  unsigned short* Wb   = (unsigned short*)(ws + 0);          //   393216
  float*          bbp  = (float*)(ws + 393216);              //     3072
  float*          ctx  = (float*)(ws + 396288);              //   262144
  unsigned short* ctxT = (unsigned short*)(ws + 658432);     //   131072
  float*          S    = (float*)(ws + 789504);              //     8192
  unsigned short* qbuf = (unsigned short*)(ws + 797696);     // 67108864
  unsigned short* xT   = (unsigned short*)(ws + 67906560);   // 67108864 -> 135015424 total

  k_prep<<<768, 256, 0, stream>>>(Wk, bk, Wq, bq, Wv, bv, Wb, bbp, ctx, S);
  k_transpose<<<NB * 256 * 4, 256, 0, stream>>>(x, xT);
  k_qkv<<<2048, 512, 0, stream>>>(xT, Wb, bbp, qbuf, ctx, S);
  k_norm<<<256, 256, 0, stream>>>(ctx, S, ctxT);
  k_att<<<NB * NHEADS * 64, 256, 0, stream>>>(x, qbuf, ctxT, out);
}

// Round 4
// 236.795 us; speedup vs baseline: 1.3232x; 1.2967x over previous
//
#include <hip/hip_runtime.h>

// EfficientAttention: N=8, C=256, H=W=128 (L=16384), HEADS=8, hc=32
// out = x + att,  att[n,h,cv,l] = sum_ck (ctx[ck,cv]/S[ck]) * softmax_ck(q)[ck,l]
// ctx[ck,cv] = sum_l exp(k[ck,l]) * v[cv,l],  S[ck] = sum_l exp(k[ck,l])

typedef __attribute__((ext_vector_type(8))) short short8;
typedef __attribute__((ext_vector_type(4))) float f32x4;

#define NB     8
#define CCH    256
#define LSP    16384
#define NHEADS 8
#define HC     32
#define NT     8      // tiles per block (32 px each -> 256 px/block)

__device__ __forceinline__ unsigned short f2bf(float f) {
  union { float f; unsigned u; } v; v.f = f;
  unsigned r = v.u + 0x7fffu + ((v.u >> 16) & 1u);   // RNE
  return (unsigned short)(r >> 16);
}
__device__ __forceinline__ float bf2f(unsigned short b) {
  union { unsigned u; float f; } v; v.u = ((unsigned)b) << 16;
  return v.f;
}
__device__ __forceinline__ unsigned cvt_pk_bf16(float lo, float hi) {
  unsigned r;
  asm("v_cvt_pk_bf16_f32 %0, %1, %2" : "=v"(r) : "v"(lo), "v"(hi));
  return r;   // low 16 = bf16(lo), high 16 = bf16(hi)
}
__device__ __forceinline__ void gload_lds16(const unsigned short* g, unsigned short* l) {
  __builtin_amdgcn_global_load_lds(
      (const __attribute__((address_space(1))) unsigned int*)g,
      (__attribute__((address_space(3))) unsigned int*)l, 16, 0, 0);
}

// ---------------- kernel 0: weights -> bf16 head-grouped [k;v;q], zero ctx/S ----------------
__global__ void k_prep(const float* __restrict__ Wk, const float* __restrict__ bk,
                       const float* __restrict__ Wq, const float* __restrict__ bq,
                       const float* __restrict__ Wv, const float* __restrict__ bv,
                       unsigned short* __restrict__ Wb, float* __restrict__ bb,
                       float* __restrict__ ctx, float* __restrict__ S) {
  int idx = blockIdx.x * 256 + threadIdx.x;
  if (idx < NHEADS * 96 * CCH) {
    int c = idx & (CCH - 1);
    int row = (idx >> 8) % 96;
    int h = idx / (96 * CCH);
    int ch = h * HC;
    float val;
    if (row < HC)          val = Wk[(ch + row) * CCH + c];
    else if (row < 2 * HC) val = Wv[(ch + row - HC) * CCH + c];
    else                   val = Wq[(ch + row - 2 * HC) * CCH + c];
    Wb[idx] = f2bf(val);
  }
  if (idx < NHEADS * 96) {
    int row = idx % 96, h = idx / 96, ch = h * HC;
    float val;
    if (row < HC)          val = bk[ch + row];
    else if (row < 2 * HC) val = bv[ch + row - HC];
    else                   val = bq[ch + row - 2 * HC];
    bb[idx] = val;
  }
  if (idx < NB * NHEADS * HC * HC) ctx[idx] = 0.f;
  if (idx < NB * NHEADS * HC)      S[idx]   = 0.f;
}

// ---------------- kernel 0b: x [n][c][l] f32 -> xT [n][l][c] bf16 ----------------
__global__ __launch_bounds__(256)
void k_transpose(const float* __restrict__ x, unsigned short* __restrict__ xT) {
  __shared__ float tile[64][65];
  int b = blockIdx.x;
  int ct = b & 3;
  int lt = (b >> 2) & 255;
  int n  = b >> 10;
  int c0 = ct * 64, l0 = lt * 64;
  int t = threadIdx.x;
  int li = t & 63, cr = t >> 6;
  const float* xp = x + (size_t)n * CCH * LSP;
#pragma unroll
  for (int i = 0; i < 16; ++i) {
    int ci = cr * 16 + i;
    tile[ci][li] = xp[(size_t)(c0 + ci) * LSP + l0 + li];
  }
  __syncthreads();
  int ci2 = t & 63, lr = t >> 6;
  unsigned short* xo = xT + ((size_t)n * LSP + l0) * CCH + c0;
#pragma unroll
  for (int i = 0; i < 16; ++i) {
    int l = lr * 16 + i;
    xo[(size_t)l * CCH + ci2] = f2bf(tile[ci2][l]);
  }
}

// ---------------- kernel 1: fused QKV GEMM, two block types ----------------
// grid 1536 = 512 groups x {kv0, kv1, q}. group = (n, 256-px range). 256 thr = 4 waves.
// KV-wave: one head's k+v (64 rows) in registers, swapped MFMA (lane holds 4 contig px),
//   exp->strips (b64), per-wave ctx MFMA accumulate, atomics once per block.
// Q-wave: two heads' q (64 rows), normal MFMA (ck in-lane), in-register softmax
//   (4 shfl), softmaxed bf16 q stored [l][ck] direct to global.
__global__ __launch_bounds__(256)
void k_fused(const unsigned short* __restrict__ xT,
             const unsigned short* __restrict__ Wb, const float* __restrict__ bb,
             unsigned short* __restrict__ qbuf, float* __restrict__ ctx,
             float* __restrict__ S) {
  __shared__ unsigned short xt[2][32 * 256];        // 32 KiB dbuf
  __shared__ unsigned short ekv[4][2][32][40];      // 20 KiB strips (pitch 40 -> b128-aligned)

  int bid = (int)blockIdx.x;
  int g = bid / 3;
  int type = bid - g * 3;          // 0,1 = kv ; 2 = q
  int n = g >> 6, lgrp = g & 63;
  int l0 = lgrp << 8;

  int tid = threadIdx.x;
  int wid = tid >> 6, lane = tid & 63;
  int r16 = lane & 15, kg = lane >> 4;
  int cS = lane & 31;

  const unsigned short* xTn = xT + (size_t)n * LSP * CCH;

  // stage 32px x 256ch bf16 tile: dest linear, source chunk-XOR-swizzled (rule 21)
  auto stage = [&](int buf, int tt) {
    int lb = l0 + tt * 32;
#pragma unroll
    for (int i = 0; i < 4; ++i) {
      int fw = i * 256 + wid * 64;                 // wave-uniform chunk base
      int px = (fw >> 5) + (lane >> 5);
      gload_lds16(xTn + ((size_t)(lb + px) << 8) + ((cS ^ (px & 7)) << 3),
                  &xt[buf][fw * 8]);
    }
  };

  if (type < 2) {
    // ================= KV path =================
    int h = type * 4 + wid;
    short8 af[4][8];     // rows rf*16+r16 of [k(32); v(32)]
#pragma unroll
    for (int rf = 0; rf < 4; ++rf)
#pragma unroll
      for (int kk = 0; kk < 8; ++kk)
        af[rf][kk] = *(const short8*)&Wb[(size_t)(h * 96 + rf * 16 + r16) * CCH + kk * 32 + kg * 8];
    float bias[4];
#pragma unroll
    for (int rf = 0; rf < 4; ++rf) bias[rf] = bb[h * 96 + rf * 16 + r16];

    f32x4 acc_ctx[2][2];
#pragma unroll
    for (int a = 0; a < 2; ++a)
#pragma unroll
      for (int b = 0; b < 2; ++b) acc_ctx[a][b] = (f32x4){0.f, 0.f, 0.f, 0.f};
    float sk0 = 0.f, sk1 = 0.f;

    stage(0, 0);
    __syncthreads();
    int cur = 0;
    for (int t = 0; t < NT; ++t) {
      if (t + 1 < NT) stage(cur ^ 1, t + 1);

      f32x4 acc[2][4];   // [pxf][rf]
#pragma unroll
      for (int a = 0; a < 2; ++a)
#pragma unroll
        for (int b = 0; b < 4; ++b) acc[a][b] = (f32x4){0.f, 0.f, 0.f, 0.f};
      const unsigned short* xb = &xt[cur][0];
#pragma unroll
      for (int kk = 0; kk < 8; ++kk) {
        int cw = (((kk * 4 + kg) ^ (r16 & 7)) << 3);
        short8 x0 = *(const short8*)&xb[r16 * 256 + cw];
        short8 x1 = *(const short8*)&xb[(16 + r16) * 256 + cw];
#pragma unroll
        for (int rf = 0; rf < 4; ++rf) {
          acc[0][rf] = __builtin_amdgcn_mfma_f32_16x16x32_bf16(x0, af[rf][kk], acc[0][rf], 0, 0, 0);
          acc[1][rf] = __builtin_amdgcn_mfma_f32_16x16x32_bf16(x1, af[rf][kk], acc[1][rf], 0, 0, 0);
        }
      }
      // scatter: lane holds (W-row = rf*16+r16, px = pxf*16+kg*4+r) -> 4 contig px = 1 b64
#pragma unroll
      for (int pxf = 0; pxf < 2; ++pxf) {
#pragma unroll
        for (int rf = 0; rf < 4; ++rf) {
          float v0 = acc[pxf][rf][0] + bias[rf];
          float v1 = acc[pxf][rf][1] + bias[rf];
          float v2 = acc[pxf][rf][2] + bias[rf];
          float v3 = acc[pxf][rf][3] + bias[rf];
          if (rf < 2) {
            float e0 = __expf(v0), e1 = __expf(v1), e2 = __expf(v2), e3 = __expf(v3);
            if (rf == 0) sk0 += e0 + e1 + e2 + e3; else sk1 += e0 + e1 + e2 + e3;
            uint2 u = {cvt_pk_bf16(e0, e1), cvt_pk_bf16(e2, e3)};
            *(uint2*)&ekv[wid][0][rf * 16 + r16][pxf * 16 + kg * 4] = u;
          } else {
            uint2 u = {cvt_pk_bf16(v0, v1), cvt_pk_bf16(v2, v3)};
            *(uint2*)&ekv[wid][1][(rf - 2) * 16 + r16][pxf * 16 + kg * 4] = u;
          }
        }
      }
      // ctx += ek (32x32px) . v^T : wave-private strips, no barrier
#pragma unroll
      for (int ckf = 0; ckf < 2; ++ckf)
#pragma unroll
        for (int cvf = 0; cvf < 2; ++cvf) {
          short8 a = *(const short8*)&ekv[wid][0][ckf * 16 + r16][kg * 8];
          short8 b = *(const short8*)&ekv[wid][1][cvf * 16 + r16][kg * 8];
          acc_ctx[ckf][cvf] = __builtin_amdgcn_mfma_f32_16x16x32_bf16(a, b, acc_ctx[ckf][cvf], 0, 0, 0);
        }
      __builtin_amdgcn_sched_barrier(0);
      asm volatile("s_waitcnt vmcnt(0)" ::: "memory");   // only next-tile DMA outstanding
      __builtin_amdgcn_sched_barrier(0);
      __builtin_amdgcn_s_barrier();
      __builtin_amdgcn_sched_barrier(0);
      cur ^= 1;
    }
    // flush: ctx quadrants + S rows (once per block)
    float* cp = ctx + ((size_t)(n * NHEADS + h) << 10);
#pragma unroll
    for (int ckf = 0; ckf < 2; ++ckf)
#pragma unroll
      for (int cvf = 0; cvf < 2; ++cvf)
#pragma unroll
        for (int rr = 0; rr < 4; ++rr)
          atomicAdd(&cp[(ckf * 16 + kg * 4 + rr) * HC + cvf * 16 + r16], acc_ctx[ckf][cvf][rr]);
#pragma unroll
    for (int rf = 0; rf < 2; ++rf) {
      float s = (rf == 0) ? sk0 : sk1;
      s += __shfl_xor(s, 16);
      s += __shfl_xor(s, 32);
      if (kg == 0) atomicAdd(&S[(n * NHEADS + h) * HC + rf * 16 + r16], s);
    }
  } else {
    // ================= Q path =================
    short8 af[4][8];     // q rows of heads 2*wid, 2*wid+1
#pragma unroll
    for (int rf = 0; rf < 4; ++rf) {
      int hq = wid * 2 + (rf >> 1);
#pragma unroll
      for (int kk = 0; kk < 8; ++kk)
        af[rf][kk] = *(const short8*)&Wb[(size_t)(hq * 96 + 64 + (rf & 1) * 16 + r16) * CCH + kk * 32 + kg * 8];
    }
    float bias[4][4];
#pragma unroll
    for (int rf = 0; rf < 4; ++rf) {
      int hq = wid * 2 + (rf >> 1);
#pragma unroll
      for (int rr = 0; rr < 4; ++rr)
        bias[rf][rr] = bb[hq * 96 + 64 + (rf & 1) * 16 + kg * 4 + rr];
    }

    stage(0, 0);
    __syncthreads();
    int cur = 0;
    for (int t = 0; t < NT; ++t) {
      int lb = l0 + t * 32;
      if (t + 1 < NT) stage(cur ^ 1, t + 1);

      f32x4 acc[4][2];   // [rf][pxf]
#pragma unroll
      for (int a = 0; a < 4; ++a)
#pragma unroll
        for (int b = 0; b < 2; ++b) acc[a][b] = (f32x4){0.f, 0.f, 0.f, 0.f};
      const unsigned short* xb = &xt[cur][0];
#pragma unroll
      for (int kk = 0; kk < 8; ++kk) {
        int cw = (((kk * 4 + kg) ^ (r16 & 7)) << 3);
        short8 x0 = *(const short8*)&xb[r16 * 256 + cw];
        short8 x1 = *(const short8*)&xb[(16 + r16) * 256 + cw];
#pragma unroll
        for (int rf = 0; rf < 4; ++rf) {
          acc[rf][0] = __builtin_amdgcn_mfma_f32_16x16x32_bf16(af[rf][kk], x0, acc[rf][0], 0, 0, 0);
          acc[rf][1] = __builtin_amdgcn_mfma_f32_16x16x32_bf16(af[rf][kk], x1, acc[rf][1], 0, 0, 0);
        }
      }
      // softmax over ck (8 in-lane + kg via 2 shfl) and store softmaxed bf16 q [l][ck]
#pragma unroll
      for (int hb = 0; hb < 2; ++hb) {
        int hq = wid * 2 + hb;
        unsigned short* qb = qbuf + (((size_t)(n * NHEADS + hq) * LSP + lb) << 5);
#pragma unroll
        for (int pxf = 0; pxf < 2; ++pxf) {
          float vl[4], vh[4];
#pragma unroll
          for (int rr = 0; rr < 4; ++rr) {
            vl[rr] = acc[hb * 2][pxf][rr] + bias[hb * 2][rr];
            vh[rr] = acc[hb * 2 + 1][pxf][rr] + bias[hb * 2 + 1][rr];
          }
          float m = fmaxf(fmaxf(fmaxf(vl[0], vl[1]), fmaxf(vl[2], vl[3])),
                          fmaxf(fmaxf(vh[0], vh[1]), fmaxf(vh[2], vh[3])));
          m = fmaxf(m, __shfl_xor(m, 16));
          m = fmaxf(m, __shfl_xor(m, 32));
          float s = 0.f;
#pragma unroll
          for (int rr = 0; rr < 4; ++rr) { vl[rr] = __expf(vl[rr] - m); s += vl[rr]; }
#pragma unroll
          for (int rr = 0; rr < 4; ++rr) { vh[rr] = __expf(vh[rr] - m); s += vh[rr]; }
          s += __shfl_xor(s, 16);
          s += __shfl_xor(s, 32);
          float inv = 1.f / s;
          uint2 ul = {cvt_pk_bf16(vl[0] * inv, vl[1] * inv), cvt_pk_bf16(vl[2] * inv, vl[3] * inv)};
          uint2 uh = {cvt_pk_bf16(vh[0] * inv, vh[1] * inv), cvt_pk_bf16(vh[2] * inv, vh[3] * inv)};
          size_t po = ((size_t)(pxf * 16 + r16) << 5) + kg * 4;
          *(uint2*)&qb[po] = ul;
          *(uint2*)&qb[po + 16] = uh;
        }
      }
      __builtin_amdgcn_sched_barrier(0);
      asm volatile("s_waitcnt vmcnt(8)" ::: "memory");   // 8 q-stores stay in flight; 4 DMA done
      __builtin_amdgcn_sched_barrier(0);
      __builtin_amdgcn_s_barrier();
      __builtin_amdgcn_sched_barrier(0);
      cur ^= 1;
    }
  }
}

// ---------------- kernel 2: ctx/S, transpose, -> bf16 ----------------
__global__ void k_norm(const float* __restrict__ ctx, const float* __restrict__ S,
                       unsigned short* __restrict__ ctxT) {
  int idx = blockIdx.x * 256 + threadIdx.x;  // 65536 = [n][h][ck][cv]
  int cv = idx & 31, ck = (idx >> 5) & 31, nh = idx >> 10;
  float v = ctx[idx] / S[(nh << 5) + ck];
  ctxT[(nh << 10) + (cv << 5) + ck] = f2bf(v);
}

// ---------------- kernel 3: att = ctxT (32x32) x q_soft (32 x L) + residual ----------------
__global__ __launch_bounds__(256)
void k_att(const float* __restrict__ x, const unsigned short* __restrict__ qbuf,
           const unsigned short* __restrict__ ctxT, float* __restrict__ out) {
  int b = blockIdx.x;
  int lc = b & 63;
  int nh = b >> 6;
  int h = nh & 7, n = nh >> 3;
  int tid = threadIdx.x, wid = tid >> 6, lane = tid & 63;
  int r16 = lane & 15, kg = lane >> 4;
  int lw = lc * 256 + wid * 64;

  const unsigned short* cp = ctxT + ((size_t)nh << 10);
  short8 a0 = *(const short8*)&cp[(r16 << 5) + kg * 8];          // A[cv][ck], cv 0-15
  short8 a1 = *(const short8*)&cp[((16 + r16) << 5) + kg * 8];   // cv 16-31
  const unsigned short* qb = qbuf + (((size_t)nh * LSP) << 5);
  const float* xp = x   + ((size_t)n * CCH + (size_t)h * HC) * LSP;
  float*       op = out + ((size_t)n * CCH + (size_t)h * HC) * LSP;

#pragma unroll
  for (int t = 0; t < 4; ++t) {
    int l = lw + t * 16;
    short8 bf = *(const short8*)&qb[((size_t)(l + r16) << 5) + kg * 8];  // softmaxed q [l][ck]
    f32x4 d0 = {0, 0, 0, 0}, d1 = {0, 0, 0, 0};
    d0 = __builtin_amdgcn_mfma_f32_16x16x32_bf16(a0, bf, d0, 0, 0, 0);
    d1 = __builtin_amdgcn_mfma_f32_16x16x32_bf16(a1, bf, d1, 0, 0, 0);
#pragma unroll
    for (int r = 0; r < 4; ++r) {
      int cv = kg * 4 + r;
      int li = l + r16;
      op[(size_t)cv * LSP + li]        = d0[r] + xp[(size_t)cv * LSP + li];
      op[(size_t)(cv + 16) * LSP + li] = d1[r] + xp[(size_t)(cv + 16) * LSP + li];
    }
  }
}

extern "C" void kernel_launch(void* const* d_in, const int* in_sizes, int n_in,
                              void* d_out, int out_size, void* d_ws, size_t ws_size,
                              hipStream_t stream) {
  (void)in_sizes; (void)n_in; (void)out_size; (void)ws_size;
  const float* x  = (const float*)d_in[0];
  const float* Wk = (const float*)d_in[1];
  const float* bk = (const float*)d_in[2];
  const float* Wq = (const float*)d_in[3];
  const float* bq = (const float*)d_in[4];
  const float* Wv = (const float*)d_in[5];
  const float* bv = (const float*)d_in[6];
  float* out = (float*)d_out;

  char* ws = (char*)d_ws;
  unsigned short* Wb   = (unsigned short*)(ws + 0);          //   393216
  float*          bbp  = (float*)(ws + 393216);              //     3072
  float*          ctx  = (float*)(ws + 396288);              //   262144
  unsigned short* ctxT = (unsigned short*)(ws + 658432);     //   131072
  float*          S    = (float*)(ws + 789504);              //     8192
  unsigned short* qbuf = (unsigned short*)(ws + 797696);     // 67108864
  unsigned short* xT   = (unsigned short*)(ws + 67906560);   // 67108864 -> 135015424 total

  k_prep<<<768, 256, 0, stream>>>(Wk, bk, Wq, bq, Wv, bv, Wb, bbp, ctx, S);
  k_transpose<<<NB * 256 * 4, 256, 0, stream>>>(x, xT);
  k_fused<<<1536, 256, 0, stream>>>(xT, Wb, bbp, qbuf, ctx, S);
  k_norm<<<256, 256, 0, stream>>>(ctx, S, ctxT);
  k_att<<<NB * NHEADS * 64, 256, 0, stream>>>(x, qbuf, ctxT, out);
}